// Round 3
// baseline (489.058 us; speedup 1.0000x reference)
//
#include <hip/hip_runtime.h>
#include <hip/hip_bf16.h>

#define NWIN 4096
#define NH 6
#define NTOK 64
#define CDIM 192
#define SCALE 0.17677669529663687f

typedef __attribute__((ext_vector_type(8))) short short8;
typedef __attribute__((ext_vector_type(4))) short short4v;
typedef __attribute__((ext_vector_type(4))) float f32x4;

__device__ __forceinline__ short bf(float x) {
  union { __hip_bfloat16 h; short s; } u;
  u.h = __float2bfloat16(x);
  return u.s;
}

__device__ __forceinline__ short8 cvt8v(f32x4 a, f32x4 b) {
  short8 r;
#pragma unroll
  for (int i = 0; i < 4; ++i) { r[i] = bf(a[i]); r[4 + i] = bf(b[i]); }
  return r;
}

// prep: qkv_w (q rows pre-scaled) + proj_w -> bf16; bias table -> [head][225] f32
__global__ void prep_weights(const float* __restrict__ qkv_w,
                             const float* __restrict__ proj_w,
                             const float* __restrict__ rel_tbl,
                             short* __restrict__ wbuf,
                             float* __restrict__ biasT) {
  const int i = blockIdx.x * 256 + threadIdx.x;
  if (i < 110592) {
    float v = qkv_w[i];
    if (i < 36864) v *= SCALE;
    wbuf[i] = bf(v);
  } else if (i < 147456) {
    wbuf[i] = bf(proj_w[i - 110592]);
  } else {
    const int j = i - 147456;
    if (j < 1350) biasT[(j % NH) * 225 + j / NH] = rel_tbl[j];
  }
}

__global__ __launch_bounds__(384, 4)
void swin_block_kernel(const float* __restrict__ x,
                       const short* __restrict__ wall,   // [576][192] qkv bf16 | [192][192] proj bf16
                       const float* __restrict__ qkv_b,
                       const float* __restrict__ proj_b,
                       const float* __restrict__ biasT,  // [6][225]
                       float* __restrict__ out) {
  __shared__ short lds[NTOK * CDIM];   // 24576 B: x tile, later ao tile

  const int b = blockIdx.x;
  const int tid = threadIdx.x;
  const int w = tid >> 6;        // wave == head
  const int lane = tid & 63;
  const int g = lane >> 4;
  const int cc = lane & 15;

  const float* xp = x + (size_t)b * (NTOK * CDIM);

  // ---------------- stage 0: cooperative x -> bf16 LDS (swizzled) ----------------
#pragma unroll
  for (int it = 0; it < 2; ++it) {
    const int flat = (tid + it * 384) * 16;
    const int r = flat / CDIM;
    const int c = flat % CDIM;
    const int X = (r & 7) << 3;
    f32x4 a0 = *(const f32x4*)(xp + flat);
    f32x4 a1 = *(const f32x4*)(xp + flat + 4);
    f32x4 a2 = *(const f32x4*)(xp + flat + 8);
    f32x4 a3 = *(const f32x4*)(xp + flat + 12);
    *(short8*)&lds[r * CDIM + (c ^ X)] = cvt8v(a0, a1);
    *(short8*)&lds[r * CDIM + ((c + 8) ^ X)] = cvt8v(a2, a3);
  }
  __syncthreads();

  // ---------------- stage 1 pass A: qT, kT via swapped MFMA ----------------
  // acc tile [ft][mt]: lane cc = token (within mt), row g*4+e = feature (within ft)
  f32x4 aq_[2][4], ak_[2][4];
#pragma unroll
  for (int ft = 0; ft < 2; ++ft)
#pragma unroll
    for (int mt = 0; mt < 4; ++mt) {
      aq_[ft][mt] = (f32x4){0.f, 0.f, 0.f, 0.f};
      ak_[ft][mt] = (f32x4){0.f, 0.f, 0.f, 0.f};
    }

#pragma unroll
  for (int ks = 0; ks < 6; ++ks) {
    short8 afr[4];
#pragma unroll
    for (int mt = 0; mt < 4; ++mt) {
      const int r = mt * 16 + cc;
      afr[mt] = *(const short8*)&lds[r * CDIM + ((ks * 32 + g * 8) ^ ((r & 7) << 3))];
    }
#pragma unroll
    for (int ft = 0; ft < 2; ++ft) {
      const int row = w * 32 + ft * 16 + cc;
      short8 wq8 = *(const short8*)&wall[row * CDIM + ks * 32 + g * 8];
      short8 wk8 = *(const short8*)&wall[(CDIM + row) * CDIM + ks * 32 + g * 8];
#pragma unroll
      for (int mt = 0; mt < 4; ++mt) {
        aq_[ft][mt] = __builtin_amdgcn_mfma_f32_16x16x32_bf16(wq8, afr[mt], aq_[ft][mt], 0, 0, 0);
        ak_[ft][mt] = __builtin_amdgcn_mfma_f32_16x16x32_bf16(wk8, afr[mt], ak_[ft][mt], 0, 0, 0);
      }
    }
  }

  // bias add + in-lane conversion to K=16 operand fragments
  short4v qf[4][2], kf[4][2];   // [token tile][feature-16 block]
  {
    f32x4 qb[2], kb[2];
#pragma unroll
    for (int ft = 0; ft < 2; ++ft) {
      f32x4 t = *(const f32x4*)&qkv_b[w * 32 + ft * 16 + g * 4];
#pragma unroll
      for (int j = 0; j < 4; ++j) t[j] *= SCALE;
      qb[ft] = t;
      kb[ft] = *(const f32x4*)&qkv_b[CDIM + w * 32 + ft * 16 + g * 4];
    }
#pragma unroll
    for (int nt = 0; nt < 4; ++nt)
#pragma unroll
      for (int ft = 0; ft < 2; ++ft)
#pragma unroll
        for (int j = 0; j < 4; ++j) {
          qf[nt][ft][j] = bf(aq_[ft][nt][j] + qb[ft][j]);
          kf[nt][ft][j] = bf(ak_[ft][nt][j] + kb[ft][j]);
        }
  }

  // ---------------- stage 1 pass B: v (normal orientation) ----------------
  // acc tile [mt][dt]: lane cc = feature (within dt), row g*4+e = token (within mt)
  f32x4 av_[4][2];
#pragma unroll
  for (int mt = 0; mt < 4; ++mt)
#pragma unroll
    for (int dt = 0; dt < 2; ++dt)
      av_[mt][dt] = (f32x4){0.f, 0.f, 0.f, 0.f};

#pragma unroll
  for (int ks = 0; ks < 6; ++ks) {
    short8 afr[4];
#pragma unroll
    for (int mt = 0; mt < 4; ++mt) {
      const int r = mt * 16 + cc;
      afr[mt] = *(const short8*)&lds[r * CDIM + ((ks * 32 + g * 8) ^ ((r & 7) << 3))];
    }
#pragma unroll
    for (int dt = 0; dt < 2; ++dt) {
      short8 wv8 = *(const short8*)&wall[(2 * CDIM + w * 32 + dt * 16 + cc) * CDIM + ks * 32 + g * 8];
#pragma unroll
      for (int mt = 0; mt < 4; ++mt)
        av_[mt][dt] = __builtin_amdgcn_mfma_f32_16x16x32_bf16(afr[mt], wv8, av_[mt][dt], 0, 0, 0);
    }
  }

  short4v vf[2][4];   // [dt feature block][kt token-16 block]
  {
    float vb[2];
    vb[0] = qkv_b[2 * CDIM + w * 32 + cc];
    vb[1] = qkv_b[2 * CDIM + w * 32 + 16 + cc];
#pragma unroll
    for (int dt = 0; dt < 2; ++dt)
#pragma unroll
      for (int kt = 0; kt < 4; ++kt)
#pragma unroll
        for (int j = 0; j < 4; ++j)
          vf[dt][kt][j] = bf(av_[kt][dt][j] + vb[dt]);
  }

  __syncthreads();   // x tile dead everywhere -> lds becomes ao

  // ---------------- stage 2: attention, fully in-register ----------------
  const float* bw = biasT + w * 225;
#pragma unroll
  for (int qh = 0; qh < 2; ++qh) {
    // S^T tiles: sacc[mt key tile][nl query tile in half]
    f32x4 sacc[4][2];
#pragma unroll
    for (int mt = 0; mt < 4; ++mt)
#pragma unroll
      for (int nl = 0; nl < 2; ++nl) {
        f32x4 z = (f32x4){0.f, 0.f, 0.f, 0.f};
        z = __builtin_amdgcn_mfma_f32_16x16x16bf16_1k(kf[mt][0], qf[qh * 2 + nl][0], z, 0, 0, 0);
        sacc[mt][nl] = __builtin_amdgcn_mfma_f32_16x16x16bf16_1k(kf[mt][1], qf[qh * 2 + nl][1], z, 0, 0, 0);
      }

    short4v pf[2][4];   // [nl][kt] P fragments
#pragma unroll
    for (int nl = 0; nl < 2; ++nl) {
      const int n = qh * 32 + nl * 16 + cc;
      const int y1 = n >> 3, x1 = n & 7;
      float mx = -1e30f;
#pragma unroll
      for (int mt = 0; mt < 4; ++mt)
#pragma unroll
        for (int e = 0; e < 4; ++e) {
          const int m = mt * 16 + g * 4 + e;
          const int idx = (y1 - (m >> 3) + 7) * 15 + (x1 - (m & 7) + 7);
          float s = sacc[mt][nl][e] + bw[idx];
          sacc[mt][nl][e] = s;
          mx = fmaxf(mx, s);
        }
      mx = fmaxf(mx, __shfl_xor(mx, 16));
      mx = fmaxf(mx, __shfl_xor(mx, 32));
      float sum = 0.f;
#pragma unroll
      for (int mt = 0; mt < 4; ++mt)
#pragma unroll
        for (int e = 0; e < 4; ++e) {
          float p = __expf(sacc[mt][nl][e] - mx);
          sacc[mt][nl][e] = p;
          sum += p;
        }
      sum += __shfl_xor(sum, 16);
      sum += __shfl_xor(sum, 32);
      const float rinv = 1.0f / sum;
#pragma unroll
      for (int kt = 0; kt < 4; ++kt)
#pragma unroll
        for (int j = 0; j < 4; ++j)
          pf[nl][kt][j] = bf(sacc[kt][nl][j] * rinv);
    }

    // PV: oacc[nl][dt], K = 64 tokens in 4 K=16 steps
    f32x4 oacc[2][2];
#pragma unroll
    for (int nl = 0; nl < 2; ++nl)
#pragma unroll
      for (int dt = 0; dt < 2; ++dt) {
        f32x4 z = (f32x4){0.f, 0.f, 0.f, 0.f};
#pragma unroll
        for (int kt = 0; kt < 4; ++kt)
          z = __builtin_amdgcn_mfma_f32_16x16x16bf16_1k(pf[nl][kt], vf[dt][kt], z, 0, 0, 0);
        oacc[nl][dt] = z;
      }

    // deposit into ao tile (swizzled)
#pragma unroll
    for (int nl = 0; nl < 2; ++nl)
#pragma unroll
      for (int dt = 0; dt < 2; ++dt)
#pragma unroll
        for (int e = 0; e < 4; ++e) {
          const int r = qh * 32 + nl * 16 + g * 4 + e;
          const int c = w * 32 + dt * 16 + cc;
          lds[r * CDIM + (c ^ ((r & 7) << 3))] = bf(oacc[nl][dt][e]);
        }
  }
  __syncthreads();

  // ---------------- stage 3: output projection ----------------
  f32x4 pacc[4][2];
#pragma unroll
  for (int mt = 0; mt < 4; ++mt)
#pragma unroll
    for (int jt = 0; jt < 2; ++jt)
      pacc[mt][jt] = (f32x4){0.f, 0.f, 0.f, 0.f};

#pragma unroll
  for (int ks = 0; ks < 6; ++ks) {
    short8 afr[4];
#pragma unroll
    for (int mt = 0; mt < 4; ++mt) {
      const int r = mt * 16 + cc;
      afr[mt] = *(const short8*)&lds[r * CDIM + ((ks * 32 + g * 8) ^ ((r & 7) << 3))];
    }
#pragma unroll
    for (int jt = 0; jt < 2; ++jt) {
      const int j = w * 32 + jt * 16 + cc;
      short8 wfr = *(const short8*)&wall[(3 * CDIM + j) * CDIM + ks * 32 + g * 8];
#pragma unroll
      for (int mt = 0; mt < 4; ++mt)
        pacc[mt][jt] = __builtin_amdgcn_mfma_f32_16x16x32_bf16(afr[mt], wfr, pacc[mt][jt], 0, 0, 0);
    }
  }

  float* op = out + (size_t)b * (NTOK * CDIM);
#pragma unroll
  for (int jt = 0; jt < 2; ++jt) {
    const int j = w * 32 + jt * 16 + cc;
    const float pb = proj_b[j];
#pragma unroll
    for (int mt = 0; mt < 4; ++mt)
#pragma unroll
      for (int e = 0; e < 4; ++e)
        op[(mt * 16 + g * 4 + e) * CDIM + j] = pacc[mt][jt][e] + pb;
  }
}

extern "C" void kernel_launch(void* const* d_in, const int* in_sizes, int n_in,
                              void* d_out, int out_size, void* d_ws, size_t ws_size,
                              hipStream_t stream) {
  const float* x       = (const float*)d_in[0];
  const float* qkv_w   = (const float*)d_in[1];
  const float* qkv_b   = (const float*)d_in[2];
  const float* proj_w  = (const float*)d_in[3];
  const float* proj_b  = (const float*)d_in[4];
  const float* rel_tbl = (const float*)d_in[5];
  float* out = (float*)d_out;

  short* wbuf  = (short*)d_ws;                    // 147456 shorts = 294912 B
  float* biasT = (float*)(wbuf + 147456);         // 1350 floats

  prep_weights<<<582, 256, 0, stream>>>(qkv_w, proj_w, rel_tbl, wbuf, biasT);
  swin_block_kernel<<<NWIN, 384, 0, stream>>>(x, wbuf, qkv_b, proj_b, biasT, out);
}

// Round 4
// 312.927 us; speedup vs baseline: 1.5629x; 1.5629x over previous
//
#include <hip/hip_runtime.h>
#include <hip/hip_bf16.h>

#define NWIN 4096
#define NH 6
#define NTOK 64
#define CDIM 192
#define SCALE 0.17677669529663687f

typedef __attribute__((ext_vector_type(8))) short short8;
typedef __attribute__((ext_vector_type(4))) short short4v;
typedef __attribute__((ext_vector_type(4))) float f32x4;

__device__ __forceinline__ short bf(float x) {
  union { __hip_bfloat16 h; short s; } u;
  u.h = __float2bfloat16(x);
  return u.s;
}

__device__ __forceinline__ short8 cvt8v(f32x4 a, f32x4 b) {
  short8 r;
#pragma unroll
  for (int i = 0; i < 4; ++i) { r[i] = bf(a[i]); r[4 + i] = bf(b[i]); }
  return r;
}

// prep: weights -> bf16 (q rows pre-scaled); bias pre-gathered into S^T
// fragment layout: biasS[h][n][m] f32, m contiguous.
__global__ void prep_weights(const float* __restrict__ qkv_w,
                             const float* __restrict__ proj_w,
                             const float* __restrict__ rel_tbl,
                             short* __restrict__ wbuf,
                             float* __restrict__ biasS) {
  const int i = blockIdx.x * 256 + threadIdx.x;   // 960*256 = 245760 exactly
  if (i < 110592) {
    float v = qkv_w[i];
    if (i < 36864) v *= SCALE;
    wbuf[i] = bf(v);
  } else if (i < 147456) {
    wbuf[i] = bf(proj_w[i - 110592]);
  } else {
    const int j = i - 147456;            // [0, 98304) = 6*64*64
    const int h = j >> 12;
    const int n = (j >> 6) & 63;
    const int m = j & 63;
    const int idx = ((n >> 3) - (m >> 3) + 7) * 15 + ((n & 7) - (m & 7) + 7);
    biasS[j] = rel_tbl[idx * NH + h];
  }
}

__global__ __launch_bounds__(384, 3)
void swin_block_kernel(const float* __restrict__ x,
                       const short* __restrict__ wall,   // qkv bf16 | proj bf16
                       const float* __restrict__ qkv_b,
                       const float* __restrict__ proj_b,
                       const float* __restrict__ biasS,  // [6][64][64] f32
                       float* __restrict__ out) {
  __shared__ short lds[NTOK * CDIM];   // 24576 B: x tile, later ao tile

  const int b = blockIdx.x;
  const int tid = threadIdx.x;
  const int w = tid >> 6;        // wave == head
  const int lane = tid & 63;
  const int g = lane >> 4;
  const int cc = lane & 15;

  const float* xp = x + (size_t)b * (NTOK * CDIM);

  // ---------------- stage 0: cooperative x -> bf16 LDS (swizzled) ----------------
#pragma unroll
  for (int it = 0; it < 2; ++it) {
    const int flat = (tid + it * 384) * 16;
    const int r = flat / CDIM;
    const int c = flat % CDIM;
    const int X = (r & 7) << 3;
    f32x4 a0 = *(const f32x4*)(xp + flat);
    f32x4 a1 = *(const f32x4*)(xp + flat + 4);
    f32x4 a2 = *(const f32x4*)(xp + flat + 8);
    f32x4 a3 = *(const f32x4*)(xp + flat + 12);
    *(short8*)&lds[r * CDIM + (c ^ X)] = cvt8v(a0, a1);
    *(short8*)&lds[r * CDIM + ((c + 8) ^ X)] = cvt8v(a2, a3);
  }
  __syncthreads();

  // ---------------- stage 1 pass A: qT, kT via swapped MFMA ----------------
  f32x4 aq_[2][4], ak_[2][4];
#pragma unroll
  for (int ft = 0; ft < 2; ++ft)
#pragma unroll
    for (int mt = 0; mt < 4; ++mt) {
      aq_[ft][mt] = (f32x4){0.f, 0.f, 0.f, 0.f};
      ak_[ft][mt] = (f32x4){0.f, 0.f, 0.f, 0.f};
    }

#pragma unroll
  for (int ks = 0; ks < 6; ++ks) {
    short8 afr[4];
#pragma unroll
    for (int mt = 0; mt < 4; ++mt) {
      const int r = mt * 16 + cc;
      afr[mt] = *(const short8*)&lds[r * CDIM + ((ks * 32 + g * 8) ^ ((r & 7) << 3))];
    }
#pragma unroll
    for (int ft = 0; ft < 2; ++ft) {
      const int row = w * 32 + ft * 16 + cc;
      short8 wq8 = *(const short8*)&wall[row * CDIM + ks * 32 + g * 8];
      short8 wk8 = *(const short8*)&wall[(CDIM + row) * CDIM + ks * 32 + g * 8];
#pragma unroll
      for (int mt = 0; mt < 4; ++mt) {
        aq_[ft][mt] = __builtin_amdgcn_mfma_f32_16x16x32_bf16(wq8, afr[mt], aq_[ft][mt], 0, 0, 0);
        ak_[ft][mt] = __builtin_amdgcn_mfma_f32_16x16x32_bf16(wk8, afr[mt], ak_[ft][mt], 0, 0, 0);
      }
    }
  }

  short4v qf[4][2], kf[4][2];   // [token tile][feature-16 block]
  {
    f32x4 qb[2], kb[2];
#pragma unroll
    for (int ft = 0; ft < 2; ++ft) {
      f32x4 t = *(const f32x4*)&qkv_b[w * 32 + ft * 16 + g * 4];
#pragma unroll
      for (int j = 0; j < 4; ++j) t[j] *= SCALE;
      qb[ft] = t;
      kb[ft] = *(const f32x4*)&qkv_b[CDIM + w * 32 + ft * 16 + g * 4];
    }
#pragma unroll
    for (int nt = 0; nt < 4; ++nt)
#pragma unroll
      for (int ft = 0; ft < 2; ++ft)
#pragma unroll
        for (int j = 0; j < 4; ++j) {
          qf[nt][ft][j] = bf(aq_[ft][nt][j] + qb[ft][j]);
          kf[nt][ft][j] = bf(ak_[ft][nt][j] + kb[ft][j]);
        }
  }

  // ---------------- stage 1 pass B: v (normal orientation) ----------------
  f32x4 av_[4][2];
#pragma unroll
  for (int mt = 0; mt < 4; ++mt)
#pragma unroll
    for (int dt = 0; dt < 2; ++dt)
      av_[mt][dt] = (f32x4){0.f, 0.f, 0.f, 0.f};

#pragma unroll
  for (int ks = 0; ks < 6; ++ks) {
    short8 afr[4];
#pragma unroll
    for (int mt = 0; mt < 4; ++mt) {
      const int r = mt * 16 + cc;
      afr[mt] = *(const short8*)&lds[r * CDIM + ((ks * 32 + g * 8) ^ ((r & 7) << 3))];
    }
#pragma unroll
    for (int dt = 0; dt < 2; ++dt) {
      short8 wv8 = *(const short8*)&wall[(2 * CDIM + w * 32 + dt * 16 + cc) * CDIM + ks * 32 + g * 8];
#pragma unroll
      for (int mt = 0; mt < 4; ++mt)
        av_[mt][dt] = __builtin_amdgcn_mfma_f32_16x16x32_bf16(afr[mt], wv8, av_[mt][dt], 0, 0, 0);
    }
  }

  short4v vf[2][4];   // [dt feature block][kt token-16 block]
  {
    float vb[2];
    vb[0] = qkv_b[2 * CDIM + w * 32 + cc];
    vb[1] = qkv_b[2 * CDIM + w * 32 + 16 + cc];
#pragma unroll
    for (int dt = 0; dt < 2; ++dt)
#pragma unroll
      for (int kt = 0; kt < 4; ++kt)
#pragma unroll
        for (int j = 0; j < 4; ++j)
          vf[dt][kt][j] = bf(av_[kt][dt][j] + vb[dt]);
  }

  __syncthreads();   // x tile dead everywhere -> lds becomes ao

  // ---------------- stage 2: attention, fully in-register ----------------
  const float* bs = biasS + w * 4096;   // [n][m], m contiguous
#pragma unroll
  for (int qh = 0; qh < 2; ++qh) {
    // S^T tiles, accumulator initialized with pre-gathered bias
    f32x4 sacc[4][2];
#pragma unroll
    for (int mt = 0; mt < 4; ++mt)
#pragma unroll
      for (int nl = 0; nl < 2; ++nl) {
        const int n = qh * 32 + nl * 16 + cc;
        f32x4 z = *(const f32x4*)&bs[n * 64 + mt * 16 + g * 4];
        z = __builtin_amdgcn_mfma_f32_16x16x16bf16_1k(kf[mt][0], qf[qh * 2 + nl][0], z, 0, 0, 0);
        sacc[mt][nl] = __builtin_amdgcn_mfma_f32_16x16x16bf16_1k(kf[mt][1], qf[qh * 2 + nl][1], z, 0, 0, 0);
      }

    short4v pf[2][4];   // [nl][kt]
#pragma unroll
    for (int nl = 0; nl < 2; ++nl) {
      float mx = -1e30f;
#pragma unroll
      for (int mt = 0; mt < 4; ++mt)
#pragma unroll
        for (int e = 0; e < 4; ++e)
          mx = fmaxf(mx, sacc[mt][nl][e]);
      mx = fmaxf(mx, __shfl_xor(mx, 16));
      mx = fmaxf(mx, __shfl_xor(mx, 32));
      float sum = 0.f;
#pragma unroll
      for (int mt = 0; mt < 4; ++mt)
#pragma unroll
        for (int e = 0; e < 4; ++e) {
          float p = __expf(sacc[mt][nl][e] - mx);
          sacc[mt][nl][e] = p;
          sum += p;
        }
      sum += __shfl_xor(sum, 16);
      sum += __shfl_xor(sum, 32);
      const float rinv = 1.0f / sum;
#pragma unroll
      for (int kt = 0; kt < 4; ++kt)
#pragma unroll
        for (int j = 0; j < 4; ++j)
          pf[nl][kt][j] = bf(sacc[kt][nl][j] * rinv);
    }

    // PV: K = 64 tokens in 4 K=16 steps
    f32x4 oacc[2][2];
#pragma unroll
    for (int nl = 0; nl < 2; ++nl)
#pragma unroll
      for (int dt = 0; dt < 2; ++dt) {
        f32x4 z = (f32x4){0.f, 0.f, 0.f, 0.f};
#pragma unroll
        for (int kt = 0; kt < 4; ++kt)
          z = __builtin_amdgcn_mfma_f32_16x16x16bf16_1k(pf[nl][kt], vf[dt][kt], z, 0, 0, 0);
        oacc[nl][dt] = z;
      }

#pragma unroll
    for (int nl = 0; nl < 2; ++nl)
#pragma unroll
      for (int dt = 0; dt < 2; ++dt)
#pragma unroll
        for (int e = 0; e < 4; ++e) {
          const int r = qh * 32 + nl * 16 + g * 4 + e;
          const int c = w * 32 + dt * 16 + cc;
          lds[r * CDIM + (c ^ ((r & 7) << 3))] = bf(oacc[nl][dt][e]);
        }
  }
  __syncthreads();

  // ---------------- stage 3: output projection ----------------
  f32x4 pacc[4][2];
#pragma unroll
  for (int mt = 0; mt < 4; ++mt)
#pragma unroll
    for (int jt = 0; jt < 2; ++jt)
      pacc[mt][jt] = (f32x4){0.f, 0.f, 0.f, 0.f};

#pragma unroll
  for (int ks = 0; ks < 6; ++ks) {
    short8 afr[4];
#pragma unroll
    for (int mt = 0; mt < 4; ++mt) {
      const int r = mt * 16 + cc;
      afr[mt] = *(const short8*)&lds[r * CDIM + ((ks * 32 + g * 8) ^ ((r & 7) << 3))];
    }
#pragma unroll
    for (int jt = 0; jt < 2; ++jt) {
      const int j = w * 32 + jt * 16 + cc;
      short8 wfr = *(const short8*)&wall[(3 * CDIM + j) * CDIM + ks * 32 + g * 8];
#pragma unroll
      for (int mt = 0; mt < 4; ++mt)
        pacc[mt][jt] = __builtin_amdgcn_mfma_f32_16x16x32_bf16(afr[mt], wfr, pacc[mt][jt], 0, 0, 0);
    }
  }

  float* op = out + (size_t)b * (NTOK * CDIM);
#pragma unroll
  for (int jt = 0; jt < 2; ++jt) {
    const int j = w * 32 + jt * 16 + cc;
    const float pb = proj_b[j];
#pragma unroll
    for (int mt = 0; mt < 4; ++mt)
#pragma unroll
      for (int e = 0; e < 4; ++e)
        op[(mt * 16 + g * 4 + e) * CDIM + j] = pacc[mt][jt][e] + pb;
  }
}

extern "C" void kernel_launch(void* const* d_in, const int* in_sizes, int n_in,
                              void* d_out, int out_size, void* d_ws, size_t ws_size,
                              hipStream_t stream) {
  const float* x       = (const float*)d_in[0];
  const float* qkv_w   = (const float*)d_in[1];
  const float* qkv_b   = (const float*)d_in[2];
  const float* proj_w  = (const float*)d_in[3];
  const float* proj_b  = (const float*)d_in[4];
  const float* rel_tbl = (const float*)d_in[5];
  float* out = (float*)d_out;

  short* wbuf  = (short*)d_ws;                    // 147456 shorts = 294912 B
  float* biasS = (float*)(wbuf + 147456);         // 98304 floats = 393216 B

  prep_weights<<<960, 256, 0, stream>>>(qkv_w, proj_w, rel_tbl, wbuf, biasS);
  swin_block_kernel<<<NWIN, 384, 0, stream>>>(x, wbuf, qkv_b, proj_b, biasS, out);
}